// Round 1
// baseline (364.956 us; speedup 1.0000x reference)
//
#include <hip/hip_runtime.h>

#define SEGS 100
#define C_TILE 4
#define BLOCK 1024
#define CHUNK 8192  // points staged per chunk (32 KB LDS of labels)

// order-preserving float->uint encoding (monotone: a<b  <=>  enc(a)<enc(b))
__device__ __forceinline__ unsigned enc_f32(float f) {
    unsigned u = __float_as_uint(f);
    return u ^ (unsigned)(((int)u >> 31) | 0x80000000);
}
__device__ __forceinline__ float dec_f32(unsigned u) {
    unsigned m = (u & 0x80000000u) ? 0x80000000u : 0xFFFFFFFFu;
    return __uint_as_float(u ^ m);
}

__global__ __launch_bounds__(BLOCK) void seg_max_kernel(
    const float* __restrict__ pf,    // (B, C, N)
    const int* __restrict__ labels,  // (B, N)
    float* __restrict__ out,         // (B*SEGS, C)
    int C, int N)
{
    __shared__ unsigned acc[C_TILE * SEGS];
    __shared__ int lab[CHUNK];

    const int tid = threadIdx.x;
    const int tiles_per_b = C / C_TILE;
    const int b = blockIdx.x / tiles_per_b;
    const int c_base = (blockIdx.x % tiles_per_b) * C_TILE;

    // init accumulators to enc(-inf) = 0x007FFFFF
    for (int i = tid; i < C_TILE * SEGS; i += BLOCK) acc[i] = 0x007FFFFFu;

    const int wave  = tid >> 6;
    const int lane  = tid & 63;
    const int cl    = wave & (C_TILE - 1);   // channel within tile
    const int strip = wave >> 2;             // n-stripe within chunk (0..3)
    const int c     = c_base + cl;

    const float4* pf4  = (const float4*)(pf + ((size_t)b * C + c) * (size_t)N);
    const int*    labg = labels + (size_t)b * N;
    unsigned*     accc = acc + cl * SEGS;

    const int it_per_chunk = CHUNK / 4 / 256;  // float4 groups per (stripe,lane) per chunk

    for (int chunk0 = 0; chunk0 < N; chunk0 += CHUNK) {
        __syncthreads();  // previous chunk's lab reads done (covers acc init on iter 0)
        // stage labels: 2048 int4 across 1024 threads
        {
            const int4* src = (const int4*)(labg + chunk0);
            int4* dst = (int4*)lab;
            dst[tid]        = src[tid];
            dst[tid + 1024] = src[tid + 1024];
        }
        __syncthreads();

        #pragma unroll
        for (int it = 0; it < it_per_chunk; ++it) {
            int idx4 = it * 256 + strip * 64 + lane;       // float4 index within chunk
            float4 f = pf4[(chunk0 >> 2) + idx4];
            int4 l4  = ((const int4*)lab)[idx4];
            if ((unsigned)l4.x < SEGS) atomicMax(&accc[l4.x], enc_f32(f.x));
            if ((unsigned)l4.y < SEGS) atomicMax(&accc[l4.y], enc_f32(f.y));
            if ((unsigned)l4.z < SEGS) atomicMax(&accc[l4.z], enc_f32(f.z));
            if ((unsigned)l4.w < SEGS) atomicMax(&accc[l4.w], enc_f32(f.w));
        }
    }

    __syncthreads();
    // write out: 400 cells per block; out[(b*SEGS + l)*C + c_base + cl]
    if (tid < C_TILE * SEGS) {
        int ocl = tid & (C_TILE - 1);
        int l   = tid >> 2;
        float v = dec_f32(acc[ocl * SEGS + l]);
        out[((size_t)(b * SEGS + l)) * C + c_base + ocl] = v;
    }
}

extern "C" void kernel_launch(void* const* d_in, const int* in_sizes, int n_in,
                              void* d_out, int out_size, void* d_ws, size_t ws_size,
                              hipStream_t stream) {
    const float* pf    = (const float*)d_in[0];   // (B, C, N) fp32
    const int*   lab   = (const int*)d_in[2];     // (B, N) int
    float*       out   = (float*)d_out;           // (B*SEGS, C) fp32

    const long long bn = in_sizes[2];             // B*N
    const int C = (int)(in_sizes[0] / bn);        // 128
    const int B = out_size / (SEGS * C);          // 8
    const int N = (int)(bn / B);                  // 65536

    const int blocks = B * (C / C_TILE);          // 256
    seg_max_kernel<<<blocks, BLOCK, 0, stream>>>(pf, lab, out, C, N);
}